// Round 10
// baseline (387.190 us; speedup 1.0000x reference)
//
#include <hip/hip_runtime.h>
#include <stdint.h>

// SIREN MLP 3->256->256->256->256->3, N=524288, fp32 in/out.
// R15: 2D wave split. 256 threads / 4 waves, 128 pts/block (R14 geometry),
// but wave (pw,cw) owns chans cw*128..+127 x pts pw*64..+63 (was 64ch x
// 128pt). Per-wave LDS h-reads HALVE (32KB/layer); block LDS traffic
// 256->128 KB/layer. W unique bytes/block and sync groups unchanged ->
// clean test of the LDS term (~170K cyc/CU of the 543K budget).
// acc[8][4]=128 regs rides in AGPRs (R14 evidence: VGPR_Count=128, no
// spill at the 256 unified cap); chan-tiles processed in two halves of 4
// to cap arch-VGPR staging at ~100.
// Budget after R14 (226us = 543K cyc/CU): trans ~262K (hard floor, 1024
// sins/pt @ 8cyc), LDS ~170K, W-L2 ~110K (halved by R14), MFMA ~61K.
// Falsified: occupancy (R9), barrier vmcnt-drain (R11), MFMA issue count
// (R12), convert_weights (R13: bench-main gap is harness overhead).
// convert_weights: output-major (R13), coalesced 16B stores.

typedef float    f32x4 __attribute__((ext_vector_type(4)));
typedef short    s16x8 __attribute__((ext_vector_type(8)));
typedef uint32_t u32x2 __attribute__((ext_vector_type(2)));
typedef uint32_t u32x4 __attribute__((ext_vector_type(4)));

#define INV2PI 0.15915494309189535f
#define L0SCALE 4.774648292756860f   /* 30/(2*pi) */
#define W4OFF 196608                 /* halfword offset of W4^T frag in ws */

__device__ __forceinline__ uint32_t pack_bf16x2(float lo, float hi) {
#if __has_builtin(__builtin_amdgcn_cvt_pk_bf16_f32)
    auto v = __builtin_amdgcn_cvt_pk_bf16_f32(lo, hi);   // lo -> low half
    return __builtin_bit_cast(uint32_t, v);
#else
    uint32_t a = __builtin_bit_cast(uint32_t, lo);
    uint32_t b = __builtin_bit_cast(uint32_t, hi);
    a += 0x7FFFu + ((a >> 16) & 1u);
    b += 0x7FFFu + ((b >> 16) & 1u);
    return (a >> 16) | (b & 0xFFFF0000u);
#endif
}
// sin with input in REVOLUTIONS (v_sin_f32); 1/(2pi) pre-folded into weights.
__device__ __forceinline__ float sin_rev(float r) {
    return __builtin_amdgcn_sinf(r);
}

// Output-major weight conversion (coalesced 16B stores, consecutive reads).
// W1..W3 region, unit u < 24576:  hw = u*8 + j, with
//   u = ((l*8+kc)*16 + cH)*64 + q*16 + n16;  c = cH*16+n16, k = kc*32+q*8+j
//   value = bf16(W_l[c*256+k] * INV2PI)   (A-frag order for 16x16x32)
// W4 region, e = u-24576 < 512:  hw = W4OFF + e*8 + j, e = kc*64 + lane,
//   n16 = lane&15, q = lane>>4;  value = n16<3 ? bf16(W4[n16*256+kc*32+q*8+j]) : 0
__global__ void convert_weights(const float* __restrict__ W1,
                                const float* __restrict__ W2,
                                const float* __restrict__ W3,
                                const float* __restrict__ W4,
                                uint16_t* __restrict__ wsb) {
    int u = blockIdx.x * blockDim.x + threadIdx.x;
    if (u < 24576) {
        int n16 = u & 15, q = (u >> 4) & 3, cH = (u >> 6) & 15,
            kc = (u >> 10) & 7, l = u >> 13;
        const float* W = (l == 0) ? W1 : (l == 1) ? W2 : W3;
        const float* src = W + (cH * 16 + n16) * 256 + kc * 32 + q * 8;
        u32x4 pk;
        #pragma unroll
        for (int j2 = 0; j2 < 4; ++j2)
            pk[j2] = pack_bf16x2(src[2 * j2] * INV2PI, src[2 * j2 + 1] * INV2PI);
        *(u32x4*)(wsb + u * 8) = pk;
    } else if (u < 25088) {
        int e = u - 24576;               // 0..511
        int lane = e & 63, kc = e >> 6;
        int n16 = lane & 15, q = lane >> 4;
        u32x4 pk = { 0u, 0u, 0u, 0u };
        if (n16 < 3) {
            const float* src = W4 + n16 * 256 + kc * 32 + q * 8;
            #pragma unroll
            for (int j2 = 0; j2 < 4; ++j2)
                pk[j2] = pack_bf16x2(src[2 * j2], src[2 * j2 + 1]);
        }
        *(u32x4*)(wsb + W4OFF + e * 8) = pk;
    }
}

// 256 threads = 4 waves, 128 points/block. Wave wid: cw=wid&1 (chan half,
// 8 ctiles of 16), pw=wid>>1 (pt half, 4 pt-tiles of 16). (256,2): 2
// blocks/CU (LDS 2x64KB); unified cap 256 = 128 acc (AGPR) + ~100 arch.
__global__ __launch_bounds__(256, 2) void siren_main(
    const float* __restrict__ x,
    const float* __restrict__ W0, const float* __restrict__ b0,
    const float* __restrict__ b1, const float* __restrict__ b2,
    const float* __restrict__ b3,
    const float* __restrict__ b4,
    const uint16_t* __restrict__ Wb,   // permuted W1..W3 + W4 frag
    float* __restrict__ out)
{
    __shared__ uint16_t h_lds[4096 * 8];   // 64 KB: unit u=(kc*8+pt)*64+q*16+n16

    const int tid  = threadIdx.x;
    const int lane = tid & 63;
    const int wid  = tid >> 6;
    const int cw   = wid & 1;          // chan half 0..1
    const int pw   = wid >> 1;         // pt half 0..1
    const int n16  = lane & 15;
    const int q    = lane >> 4;
    const int p0   = blockIdx.x * 128;     // 4096 * 128 = 524288 exact

    // ------- Layer 0 (fp32): h1 = sin_rev( (30/2pi)*(W0 x + b0) ) ----------
    // (unchanged from R14: 32 chan-octets over 4 waves x 2 oo x 4 q, all 8 rt)
    {
        float xv[8][3];
        #pragma unroll
        for (int rt = 0; rt < 8; ++rt) {
            const float* xp = x + (p0 + rt * 16 + n16) * 3;
            xv[rt][0] = xp[0]; xv[rt][1] = xp[1]; xv[rt][2] = xp[2];
        }
        #pragma unroll
        for (int oo = 0; oo < 2; ++oo) {
            const int octet = wid * 8 + oo * 4 + q;      // chan-octet 0..31
            const float* w0r = W0 + octet * 24;
            float wv[24];
            #pragma unroll
            for (int i = 0; i < 24; ++i) wv[i] = w0r[i] * L0SCALE;
            float bb[8];
            #pragma unroll
            for (int i = 0; i < 8; ++i) bb[i] = b0[octet * 8 + i] * L0SCALE;
            const int kc0 = octet >> 2, q0 = octet & 3;
            #pragma unroll
            for (int rt = 0; rt < 8; ++rt) {
                u32x4 pk;
                #pragma unroll
                for (int j2 = 0; j2 < 4; ++j2) {
                    float za = wv[(2*j2  )*3+0] * xv[rt][0] +
                               wv[(2*j2  )*3+1] * xv[rt][1] +
                               wv[(2*j2  )*3+2] * xv[rt][2] + bb[2*j2];
                    float zb = wv[(2*j2+1)*3+0] * xv[rt][0] +
                               wv[(2*j2+1)*3+1] * xv[rt][1] +
                               wv[(2*j2+1)*3+2] * xv[rt][2] + bb[2*j2+1];
                    pk[j2] = pack_bf16x2(sin_rev(za), sin_rev(zb));
                }
                *(u32x4*)&h_lds[((kc0 * 8 + rt) * 64 + q0 * 16 + n16) * 8] = pk;
            }
        }
    }
    __syncthreads();

    // ------- Hidden layers (bf16 MFMA 16x16x32, D[chan][pt]) ----------------
    #pragma unroll
    for (int l = 0; l < 3; ++l) {
        const uint16_t* wsl = Wb + l * 65536;
        const float* bl = (l == 0) ? b1 : (l == 1) ? b2 : b3;

        // acc init = bias (pre-scaled): rides the MFMA C input
        f32x4 acc[8][4];       // [chan-tile t][pt-tile pt] = 128 regs (AGPR)
        #pragma unroll
        for (int t = 0; t < 8; ++t) {
            f32x4 bv = *(const f32x4*)&bl[cw * 128 + t * 16 + q * 4];
            bv *= INV2PI;
            #pragma unroll
            for (int pt = 0; pt < 4; ++pt) acc[t][pt] = bv;
        }

        #pragma unroll
        for (int kc = 0; kc < 8; ++kc) {
            // B-frags for this wave's 4 pt-tiles (re-used by both ct halves)
            s16x8 hf[4];
            #pragma unroll
            for (int pt = 0; pt < 4; ++pt)
                hf[pt] = *(const s16x8*)&h_lds[
                    ((kc * 8 + pw * 4 + pt) * 64 + lane) * 8];
            // chan-tile half A: t = 0..3 (wf 32 regs live)
            {
                s16x8 wf[4];
                #pragma unroll
                for (int t = 0; t < 4; ++t)
                    wf[t] = *(const s16x8*)(wsl +
                        ((kc * 16 + cw * 8 + t) * 64 + lane) * 8);
                #pragma unroll
                for (int t = 0; t < 4; ++t)
                    #pragma unroll
                    for (int pt = 0; pt < 4; ++pt)
                        acc[t][pt] = __builtin_amdgcn_mfma_f32_16x16x32_bf16(
                            wf[t], hf[pt], acc[t][pt], 0, 0, 0);
            }
            // chan-tile half B: t = 4..7
            {
                s16x8 wf[4];
                #pragma unroll
                for (int t = 0; t < 4; ++t)
                    wf[t] = *(const s16x8*)(wsl +
                        ((kc * 16 + cw * 8 + 4 + t) * 64 + lane) * 8);
                #pragma unroll
                for (int t = 0; t < 4; ++t)
                    #pragma unroll
                    for (int pt = 0; pt < 4; ++pt)
                        acc[4 + t][pt] = __builtin_amdgcn_mfma_f32_16x16x32_bf16(
                            wf[t], hf[pt], acc[4 + t][pt], 0, 0, 0);
            }
        }
        __syncthreads();   // all h reads done before overwrite

        // epilogue: sin (bias already in acc), write h_next in B-frag layout.
        // chan c = cw*128 + t*16 + q*4 + r -> kcp = cw*4 + (t>>1),
        // qp = (t&1)*2 + (q>>1), j = (q&1)*4 + r; pt-tile = pw*4 + pt.
        uint32_t* hw = (uint32_t*)h_lds;
        #pragma unroll
        for (int t = 0; t < 8; ++t) {
            const int kcp = cw * 4 + (t >> 1);
            const int qp  = (t & 1) * 2 + (q >> 1);
            #pragma unroll
            for (int pt = 0; pt < 4; ++pt) {
                float s0 = sin_rev(acc[t][pt][0]);
                float s1 = sin_rev(acc[t][pt][1]);
                float s2 = sin_rev(acc[t][pt][2]);
                float s3 = sin_rev(acc[t][pt][3]);
                int base = ((kcp * 8 + pw * 4 + pt) * 64 + qp * 16 + n16) * 4
                           + (q & 1) * 2;
                u32x2 w2 = { pack_bf16x2(s0, s1), pack_bf16x2(s2, s3) };
                *(u32x2*)&hw[base] = w2;   // 8B write, r=0..3
            }
        }
        __syncthreads();
    }

    // ------- Final layer via MFMA: out = W4 h4 + b4 -------------------------
    // 8 pt-tiles; wave wid handles tiles wid*2 and wid*2+1 (as R14).
    {
        float bb4 = (n16 < 3) ? b4[n16] : 0.0f;
        f32x4 accF[2] = { { bb4, bb4, bb4, bb4 }, { bb4, bb4, bb4, bb4 } };
        #pragma unroll
        for (int kc = 0; kc < 8; ++kc) {
            s16x8 w4f = *(const s16x8*)(Wb + W4OFF + (kc * 64 + lane) * 8);
            #pragma unroll
            for (int hh = 0; hh < 2; ++hh) {
                s16x8 af = *(const s16x8*)&h_lds[
                    ((kc * 8 + wid * 2 + hh) * 64 + lane) * 8];
                accF[hh] = __builtin_amdgcn_mfma_f32_16x16x32_bf16(
                    af, w4f, accF[hh], 0, 0, 0);
            }
        }
        // D: row=q*4+r -> pt-in-tile (tile wid*2+hh), col=n16 -> out-chan
        if (n16 < 3) {
            #pragma unroll
            for (int hh = 0; hh < 2; ++hh)
                #pragma unroll
                for (int r = 0; r < 4; ++r)
                    out[(p0 + (wid * 2 + hh) * 16 + q * 4 + r) * 3 + n16] = accF[hh][r];
        }
    }
}

extern "C" void kernel_launch(void* const* d_in, const int* in_sizes, int n_in,
                              void* d_out, int out_size, void* d_ws, size_t ws_size,
                              hipStream_t stream) {
    const float* x  = (const float*)d_in[0];
    const float* W0 = (const float*)d_in[1];
    const float* b0 = (const float*)d_in[2];
    const float* W1 = (const float*)d_in[3];
    const float* b1 = (const float*)d_in[4];
    const float* W2 = (const float*)d_in[5];
    const float* b2 = (const float*)d_in[6];
    const float* W3 = (const float*)d_in[7];
    const float* b3 = (const float*)d_in[8];
    const float* W4 = (const float*)d_in[9];
    const float* b4 = (const float*)d_in[10];
    float* outp     = (float*)d_out;
    uint16_t* wsb   = (uint16_t*)d_ws;   // needs 402 KB

    hipLaunchKernelGGL(convert_weights, dim3(98), dim3(256), 0, stream,
                       W1, W2, W3, W4, wsb);
    hipLaunchKernelGGL(siren_main, dim3(4096), dim3(256), 0, stream,
                       x, W0, b0, b1, b2, b3, b4, wsb, outp);
}

// Round 11
// 276.234 us; speedup vs baseline: 1.4017x; 1.4017x over previous
//
#include <hip/hip_runtime.h>
#include <stdint.h>

// SIREN MLP 3->256->256->256->256->3, N=524288, fp32 in/out.
// R16 = R14 (proven 226us) + zero-register-cost cross-barrier W prefetch:
//   - layer-0 first-kc W load hoisted ABOVE L0 (hidden under L0 compute)
//   - at kc==7 (dbuf nxt slot dead in R14) prefetch next layer's kc0;
//     loads fly across both epilogue barriers (R11-proven pattern)
//   - at l==2, kc==7 prefetch W4 frags 0..3 into the slot; L4 uses them.
// R14 recap: 256 thr / 4 waves / 128 pts, wave = 64ch x 128pt, acc[4][8]
// =128 AGPR + 128 arch = exactly the 256 unified cap, single-kc W dbuf
// (32 MFMAs ~160cyc cover L2 latency), h in 64KB LDS, 2 blocks/CU.
// R15 FAILED (373us): 2D split deleted the W dbuf (exposed ~200cyc/half-kc,
// MfmaUtil 43->24) + mild spill (WRITE 6->13MB). Register sweep: every
// LDS-halving tile needs acc128+Wdbuf128+hf32 > 256 -> infeasible.
// Falsified levers: occupancy (R9), L2-bytes (R10), barrier vmcnt-drain
// (R11 on R5; retesting mechanism here on 2-block R14 where exposure is
// larger), MFMA count (R12), LDS-read count (R12/R15), convert_weights (R13).

typedef float    f32x4 __attribute__((ext_vector_type(4)));
typedef short    s16x8 __attribute__((ext_vector_type(8)));
typedef uint32_t u32x2 __attribute__((ext_vector_type(2)));
typedef uint32_t u32x4 __attribute__((ext_vector_type(4)));

#define INV2PI 0.15915494309189535f
#define L0SCALE 4.774648292756860f   /* 30/(2*pi) */
#define W4OFF 196608                 /* halfword offset of W4^T frag in ws */

__device__ __forceinline__ uint32_t pack_bf16x2(float lo, float hi) {
#if __has_builtin(__builtin_amdgcn_cvt_pk_bf16_f32)
    auto v = __builtin_amdgcn_cvt_pk_bf16_f32(lo, hi);   // lo -> low half
    return __builtin_bit_cast(uint32_t, v);
#else
    uint32_t a = __builtin_bit_cast(uint32_t, lo);
    uint32_t b = __builtin_bit_cast(uint32_t, hi);
    a += 0x7FFFu + ((a >> 16) & 1u);
    b += 0x7FFFu + ((b >> 16) & 1u);
    return (a >> 16) | (b & 0xFFFF0000u);
#endif
}
// sin with input in REVOLUTIONS (v_sin_f32); 1/(2pi) pre-folded into weights.
__device__ __forceinline__ float sin_rev(float r) {
    return __builtin_amdgcn_sinf(r);
}

// Output-major weight conversion (coalesced 16B stores, consecutive reads).
// W1..W3 region, unit u < 24576:  hw = u*8 + j, with
//   u = ((l*8+kc)*16 + cH)*64 + q*16 + n16;  c = cH*16+n16, k = kc*32+q*8+j
//   value = bf16(W_l[c*256+k] * INV2PI)   (A-frag order for 16x16x32)
// W4 region, e = u-24576 < 512:  hw = W4OFF + e*8 + j, e = kc*64 + lane,
//   n16 = lane&15, q = lane>>4;  value = n16<3 ? bf16(W4[n16*256+kc*32+q*8+j]) : 0
__global__ void convert_weights(const float* __restrict__ W1,
                                const float* __restrict__ W2,
                                const float* __restrict__ W3,
                                const float* __restrict__ W4,
                                uint16_t* __restrict__ wsb) {
    int u = blockIdx.x * blockDim.x + threadIdx.x;
    if (u < 24576) {
        int n16 = u & 15, q = (u >> 4) & 3, cH = (u >> 6) & 15,
            kc = (u >> 10) & 7, l = u >> 13;
        const float* W = (l == 0) ? W1 : (l == 1) ? W2 : W3;
        const float* src = W + (cH * 16 + n16) * 256 + kc * 32 + q * 8;
        u32x4 pk;
        #pragma unroll
        for (int j2 = 0; j2 < 4; ++j2)
            pk[j2] = pack_bf16x2(src[2 * j2] * INV2PI, src[2 * j2 + 1] * INV2PI);
        *(u32x4*)(wsb + u * 8) = pk;
    } else if (u < 25088) {
        int e = u - 24576;               // 0..511
        int lane = e & 63, kc = e >> 6;
        int n16 = lane & 15, q = lane >> 4;
        u32x4 pk = { 0u, 0u, 0u, 0u };
        if (n16 < 3) {
            const float* src = W4 + n16 * 256 + kc * 32 + q * 8;
            #pragma unroll
            for (int j2 = 0; j2 < 4; ++j2)
                pk[j2] = pack_bf16x2(src[2 * j2], src[2 * j2 + 1]);
        }
        *(u32x4*)(wsb + W4OFF + e * 8) = pk;
    }
}

// 256 threads = 4 waves, 128 points/block. Wave wid owns chans wid*64..+63
// across ALL 128 pts (8 pt-tiles of 16). (256,2): 2 blocks/CU (LDS 2x64KB),
// unified VGPR cap 256/wave = 128 acc (AGPR) + 128 arch (R14 measured).
__global__ __launch_bounds__(256, 2) void siren_main(
    const float* __restrict__ x,
    const float* __restrict__ W0, const float* __restrict__ b0,
    const float* __restrict__ b1, const float* __restrict__ b2,
    const float* __restrict__ b3,
    const float* __restrict__ b4,
    const uint16_t* __restrict__ Wb,   // permuted W1..W3 + W4 frag
    float* __restrict__ out)
{
    __shared__ uint16_t h_lds[4096 * 8];   // 64 KB: unit u=(kc*8+pt)*64+q*16+n16

    const int tid  = threadIdx.x;
    const int lane = tid & 63;
    const int wid  = tid >> 6;
    const int n16  = lane & 15;
    const int q    = lane >> 4;
    const int p0   = blockIdx.x * 128;     // 4096 * 128 = 524288 exact

    // W dbuf lives across the whole kernel; the global-load pipeline is
    // never broken by a barrier. Layer-0 kc0 issued NOW, hidden under L0.
    s16x8 Wbuf[2][4];   // [buf][chan-tile]
    #pragma unroll
    for (int t = 0; t < 4; ++t)
        Wbuf[0][t] = *(const s16x8*)(Wb + ((wid * 4 + t) * 64 + lane) * 8);

    // ------- Layer 0 (fp32): h1 = sin_rev( (30/2pi)*(W0 x + b0) ) ----------
    {
        float xv[8][3];
        #pragma unroll
        for (int rt = 0; rt < 8; ++rt) {
            const float* xp = x + (p0 + rt * 16 + n16) * 3;
            xv[rt][0] = xp[0]; xv[rt][1] = xp[1]; xv[rt][2] = xp[2];
        }
        #pragma unroll
        for (int oo = 0; oo < 2; ++oo) {
            const int octet = wid * 8 + oo * 4 + q;      // chan-octet 0..31
            const float* w0r = W0 + octet * 24;
            float wv[24];
            #pragma unroll
            for (int i = 0; i < 24; ++i) wv[i] = w0r[i] * L0SCALE;
            float bb[8];
            #pragma unroll
            for (int i = 0; i < 8; ++i) bb[i] = b0[octet * 8 + i] * L0SCALE;
            const int kc0 = octet >> 2, q0 = octet & 3;
            #pragma unroll
            for (int rt = 0; rt < 8; ++rt) {
                u32x4 pk;
                #pragma unroll
                for (int j2 = 0; j2 < 4; ++j2) {
                    float za = wv[(2*j2  )*3+0] * xv[rt][0] +
                               wv[(2*j2  )*3+1] * xv[rt][1] +
                               wv[(2*j2  )*3+2] * xv[rt][2] + bb[2*j2];
                    float zb = wv[(2*j2+1)*3+0] * xv[rt][0] +
                               wv[(2*j2+1)*3+1] * xv[rt][1] +
                               wv[(2*j2+1)*3+2] * xv[rt][2] + bb[2*j2+1];
                    pk[j2] = pack_bf16x2(sin_rev(za), sin_rev(zb));
                }
                *(u32x4*)&h_lds[((kc0 * 8 + rt) * 64 + q0 * 16 + n16) * 8] = pk;
            }
        }
    }
    __syncthreads();

    // ------- Hidden layers (bf16 MFMA 16x16x32, D[chan][pt]) ----------------
    #pragma unroll
    for (int l = 0; l < 3; ++l) {
        const uint16_t* wsl = Wb + l * 65536;
        const float* bl = (l == 0) ? b1 : (l == 1) ? b2 : b3;

        // acc init = bias (pre-scaled): rides the MFMA C input
        f32x4 acc[4][8];       // [chan-tile t][pt-tile pt]  = 128 regs (AGPR)
        #pragma unroll
        for (int t = 0; t < 4; ++t) {
            f32x4 bv = *(const f32x4*)&bl[wid * 64 + t * 16 + q * 4];
            bv *= INV2PI;
            #pragma unroll
            for (int pt = 0; pt < 8; ++pt) acc[t][pt] = bv;
        }

        // Wbuf[0] already holds this layer's kc0 (prefetched across the
        // barrier at the previous layer's kc==7, or pre-L0 for l==0).
        #pragma unroll
        for (int kc = 0; kc < 8; ++kc) {
            const int cur = kc & 1, nxt = cur ^ 1;
            if (kc < 7) {                     // prefetch next kc under MFMA
                #pragma unroll
                for (int t = 0; t < 4; ++t)
                    Wbuf[nxt][t] = *(const s16x8*)(wsl +
                        (((kc + 1) * 16 + wid * 4 + t) * 64 + lane) * 8);
            } else if (l < 2) {
                // kc==7: nxt slot is dead -> prefetch NEXT layer's kc0;
                // loads fly across both epilogue barriers.
                const uint16_t* wsn = Wb + (l + 1) * 65536;
                #pragma unroll
                for (int t = 0; t < 4; ++t)
                    Wbuf[nxt][t] = *(const s16x8*)(wsn +
                        ((wid * 4 + t) * 64 + lane) * 8);
            } else {
                // l==2, kc==7: prefetch W4^T frags 0..3 (kc=t) into the slot.
                #pragma unroll
                for (int t = 0; t < 4; ++t)
                    Wbuf[nxt][t] = *(const s16x8*)(Wb + W4OFF +
                        ((t * 64 + lane) * 8));
            }
            // half A: pt-tiles 0..3 (caps hf liveness at 32 VGPR)
            {
                s16x8 hf[4];
                #pragma unroll
                for (int pt = 0; pt < 4; ++pt)
                    hf[pt] = *(const s16x8*)&h_lds[((kc * 8 + pt) * 64 + lane) * 8];
                #pragma unroll
                for (int t = 0; t < 4; ++t)
                    #pragma unroll
                    for (int pt = 0; pt < 4; ++pt)
                        acc[t][pt] = __builtin_amdgcn_mfma_f32_16x16x32_bf16(
                            Wbuf[cur][t], hf[pt], acc[t][pt], 0, 0, 0);
            }
            // half B: pt-tiles 4..7
            {
                s16x8 hf[4];
                #pragma unroll
                for (int pt = 0; pt < 4; ++pt)
                    hf[pt] = *(const s16x8*)&h_lds[((kc * 8 + 4 + pt) * 64 + lane) * 8];
                #pragma unroll
                for (int t = 0; t < 4; ++t)
                    #pragma unroll
                    for (int pt = 0; pt < 4; ++pt)
                        acc[t][4 + pt] = __builtin_amdgcn_mfma_f32_16x16x32_bf16(
                            Wbuf[cur][t], hf[pt], acc[t][4 + pt], 0, 0, 0);
            }
        }
        __syncthreads();   // all h reads done before overwrite

        // epilogue: sin (bias already in acc), write h_next in B-frag layout.
        // chan c = wid*64 + t*16 + q*4 + r -> kcp = wid*2+(t>>1),
        // qp = (t*2+(q>>1))&3, j = (q&1)*4 + r.
        uint32_t* hw = (uint32_t*)h_lds;
        #pragma unroll
        for (int t = 0; t < 4; ++t) {
            const int kcp = wid * 2 + (t >> 1);
            const int qp  = (t * 2 + (q >> 1)) & 3;
            #pragma unroll
            for (int pt = 0; pt < 8; ++pt) {
                float s0 = sin_rev(acc[t][pt][0]);
                float s1 = sin_rev(acc[t][pt][1]);
                float s2 = sin_rev(acc[t][pt][2]);
                float s3 = sin_rev(acc[t][pt][3]);
                int base = ((kcp * 8 + pt) * 64 + qp * 16 + n16) * 4 + (q & 1) * 2;
                u32x2 w2 = { pack_bf16x2(s0, s1), pack_bf16x2(s2, s3) };
                *(u32x2*)&hw[base] = w2;   // 8B write, r=0..3
            }
        }
        __syncthreads();
    }

    // ------- Final layer via MFMA: out = W4 h4 + b4 -------------------------
    // W4 frags 0..3 register-resident in Wbuf[0]; 4..7 loaded here (their
    // loads issue up-front, no barrier in between).
    {
        float bb4 = (n16 < 3) ? b4[n16] : 0.0f;
        f32x4 accF[2] = { { bb4, bb4, bb4, bb4 }, { bb4, bb4, bb4, bb4 } };
        #pragma unroll
        for (int kc = 0; kc < 8; ++kc) {
            s16x8 w4f = (kc < 4) ? Wbuf[0][kc]
                : *(const s16x8*)(Wb + W4OFF + (kc * 64 + lane) * 8);
            #pragma unroll
            for (int hh = 0; hh < 2; ++hh) {
                s16x8 af = *(const s16x8*)&h_lds[
                    ((kc * 8 + wid * 2 + hh) * 64 + lane) * 8];
                accF[hh] = __builtin_amdgcn_mfma_f32_16x16x32_bf16(
                    af, w4f, accF[hh], 0, 0, 0);
            }
        }
        // D: row=q*4+r -> pt-in-tile (tile wid*2+hh), col=n16 -> out-chan
        if (n16 < 3) {
            #pragma unroll
            for (int hh = 0; hh < 2; ++hh)
                #pragma unroll
                for (int r = 0; r < 4; ++r)
                    out[(p0 + (wid * 2 + hh) * 16 + q * 4 + r) * 3 + n16] = accF[hh][r];
        }
    }
}

extern "C" void kernel_launch(void* const* d_in, const int* in_sizes, int n_in,
                              void* d_out, int out_size, void* d_ws, size_t ws_size,
                              hipStream_t stream) {
    const float* x  = (const float*)d_in[0];
    const float* W0 = (const float*)d_in[1];
    const float* b0 = (const float*)d_in[2];
    const float* W1 = (const float*)d_in[3];
    const float* b1 = (const float*)d_in[4];
    const float* W2 = (const float*)d_in[5];
    const float* b2 = (const float*)d_in[6];
    const float* W3 = (const float*)d_in[7];
    const float* b3 = (const float*)d_in[8];
    const float* W4 = (const float*)d_in[9];
    const float* b4 = (const float*)d_in[10];
    float* outp     = (float*)d_out;
    uint16_t* wsb   = (uint16_t*)d_ws;   // needs 402 KB

    hipLaunchKernelGGL(convert_weights, dim3(98), dim3(256), 0, stream,
                       W1, W2, W3, W4, wsb);
    hipLaunchKernelGGL(siren_main, dim3(4096), dim3(256), 0, stream,
                       x, W0, b0, b1, b2, b3, b4, wsb, outp);
}